// Round 1
// 173.760 us; speedup vs baseline: 1.0149x; 1.0149x over previous
//
#include <hip/hip_runtime.h>
#include <math.h>

// Problem constants (match reference)
constexpr int B = 64, J = 8, K = 64, M = 32, D = 256;
constexpr int NNEG = K * M;            // 2048 negatives per batch
constexpr float TEMP = 0.1f;
constexpr float EPS = 1e-8f;
constexpr float SHIFT = 10.0f;         // 1/TEMP upper bound on |sim|

constexpr int SLICES = 8;                       // blocks per batch
constexpr int NEG_PER_BLOCK = NNEG / SLICES;    // 256 negs / block
constexpr int NBLK = B * SLICES;                // 512 blocks

// Kernel 1: per-(batch, slice) partial sum of exp(neg_sim - SHIFT) over
// label-matching negatives. Labels checked BEFORE reading the 1 KB vectors
// -> only ~1/16 of the 128 MB negs array is fetched. Zero LDS, zero
// barriers.
//
// v2: 16-lane-group dot products. Each wave splits into 4 groups of 16
// lanes; lane gl of a group holds child/neg elems {gl*4 + 64q | q=0..3}.
// A round processes 8 matched negatives (2 per group): same load bytes as
// before (8 x float4 per lane) but the shuffle reduce is a 4-level
// in-group butterfly -> 16 ds_bpermute per round instead of 96, and the
// expf tail runs 4-wide (one group leader each) instead of 8-serial on
// lane 0.
__global__ __launch_bounds__(256) void neg_partial_kernel(
    const float* __restrict__ childrens,
    const float* __restrict__ childrens_pos,
    const int*   __restrict__ gt_labels,
    const float* __restrict__ negs,
    const int*   __restrict__ neg_labels,
    float*       __restrict__ partials,
    float*       __restrict__ pos_sims) {
  const int blk  = blockIdx.x;
  const int b    = blk >> 3;       // / SLICES
  const int s    = blk & 7;        // % SLICES
  const int tid  = threadIdx.x;    // 0..255
  const int lane = tid & 63;
  const int wave = tid >> 6;       // 0..3
  const int g    = lane >> 4;      // 16-lane group 0..3
  const int gl   = lane & 15;      // lane within group

  // ---- issue all independent loads up front ----
  const float* child = childrens + ((size_t)b * J + (J - 1)) * D;
  // lane holds child elems gl*4 + 64*q (q=0..3); all 4 groups hold the
  // full vector (redundant reads are L1 hits).
  float4 cv[4];
  #pragma unroll
  for (int q = 0; q < 4; ++q) cv[q] = ((const float4*)child)[gl + 16 * q];

  const int label = gt_labels[b * J + (J - 1)];
  const int neg_base = s * NEG_PER_BLOCK + wave * 64;
  const int nlab = neg_labels[(size_t)b * NNEG + neg_base + lane];

  const bool do_pos = (s == 0) && (wave == 0);
  float4 pv[4] = {make_float4(0.f,0.f,0.f,0.f), make_float4(0.f,0.f,0.f,0.f),
                  make_float4(0.f,0.f,0.f,0.f), make_float4(0.f,0.f,0.f,0.f)};
  if (do_pos) {
    const float* posp = childrens_pos + ((size_t)b * J + (J - 1)) * D;
    #pragma unroll
    for (int q = 0; q < 4; ++q) pv[q] = ((const float4*)posp)[gl + 16 * q];
  }

  // ---- child norm^2 via 4-level in-group butterfly (valid in ALL lanes)
  float ss = 0.f;
  #pragma unroll
  for (int q = 0; q < 4; ++q)
    ss += cv[q].x*cv[q].x + cv[q].y*cv[q].y + cv[q].z*cv[q].z + cv[q].w*cv[q].w;
  #pragma unroll
  for (int off = 8; off > 0; off >>= 1) ss += __shfl_xor(ss, off, 64);
  const float cn_inv_t = 1.0f / (fmaxf(sqrtf(ss), EPS) * TEMP);

  const float* nv_base = negs + (size_t)b * NNEG * D;
  unsigned long long mask = __ballot(nlab == label);

  float acc = 0.0f;
  while (mask) {
    // peel up to 8 set bits (wave-uniform); pad with idx[0] (cache-hit
    // reloads, guarded out of the accumulate below)
    int idx[8];
    int cnt = 1;
    idx[0] = __ffsll((long long)mask) - 1;
    mask &= mask - 1;
    #pragma unroll
    for (int t = 1; t < 8; ++t) {
      if (mask) {
        idx[t] = __ffsll((long long)mask) - 1;
        mask &= mask - 1;
        ++cnt;
      } else {
        idx[t] = idx[0];
      }
    }

    // group g takes slots g and 4+g. Select via cndmask chain (no
    // runtime-indexed array -> no scratch).
    const int my0 = (g == 0) ? idx[0] : (g == 1) ? idx[1] : (g == 2) ? idx[2] : idx[3];
    const int my1 = (g == 0) ? idx[4] : (g == 1) ? idx[5] : (g == 2) ? idx[6] : idx[7];

    const float* p0 = nv_base + (size_t)(neg_base + my0) * D;
    const float* p1 = nv_base + (size_t)(neg_base + my1) * D;

    // 8 independent float4 loads in flight per lane (same bytes as v1)
    float4 x0[4], x1[4];
    #pragma unroll
    for (int q = 0; q < 4; ++q) {
      x0[q] = ((const float4*)p0)[gl + 16 * q];
      x1[q] = ((const float4*)p1)[gl + 16 * q];
    }

    float dot0 = 0.f, nn0 = 0.f, dot1 = 0.f, nn1 = 0.f;
    #pragma unroll
    for (int q = 0; q < 4; ++q) {
      dot0 += cv[q].x*x0[q].x + cv[q].y*x0[q].y + cv[q].z*x0[q].z + cv[q].w*x0[q].w;
      nn0  += x0[q].x*x0[q].x + x0[q].y*x0[q].y + x0[q].z*x0[q].z + x0[q].w*x0[q].w;
      dot1 += cv[q].x*x1[q].x + cv[q].y*x1[q].y + cv[q].z*x1[q].z + cv[q].w*x1[q].w;
      nn1  += x1[q].x*x1[q].x + x1[q].y*x1[q].y + x1[q].z*x1[q].z + x1[q].w*x1[q].w;
    }
    // 4-level in-group butterfly: 16 shuffles per round of 8 negatives
    #pragma unroll
    for (int off = 8; off > 0; off >>= 1) {
      dot0 += __shfl_xor(dot0, off, 64);
      nn0  += __shfl_xor(nn0,  off, 64);
      dot1 += __shfl_xor(dot1, off, 64);
      nn1  += __shfl_xor(nn1,  off, 64);
    }
    if (gl == 0) {
      if (g < cnt)
        acc += expf(dot0 * cn_inv_t / fmaxf(sqrtf(nn0), EPS) - SHIFT);
      if (4 + g < cnt)
        acc += expf(dot1 * cn_inv_t / fmaxf(sqrtf(nn1), EPS) - SHIFT);
    }
  }

  // ---- combine the 4 group leaders (lanes 0,16,32,48) ----
  acc += __shfl_xor(acc, 16, 64);
  acc += __shfl_xor(acc, 32, 64);

  // ---- pos_sim (one wave per batch) ----
  if (do_pos) {
    float pp = 0.f, cp = 0.f;
    #pragma unroll
    for (int q = 0; q < 4; ++q) {
      pp += pv[q].x*pv[q].x + pv[q].y*pv[q].y + pv[q].z*pv[q].z + pv[q].w*pv[q].w;
      cp += cv[q].x*pv[q].x + cv[q].y*pv[q].y + cv[q].z*pv[q].z + cv[q].w*pv[q].w;
    }
    #pragma unroll
    for (int off = 8; off > 0; off >>= 1) {
      pp += __shfl_xor(pp, off, 64);
      cp += __shfl_xor(cp, off, 64);
    }
    if (lane == 0) {
      const float pos_sim = cp * cn_inv_t / fmaxf(sqrtf(pp), EPS);
      pos_sims[b] = pos_sim;
      acc += expf(pos_sim - SHIFT);
    }
  }

  if (lane == 0) partials[blk * 4 + wave] = acc;
}

// Kernel 2: one wave; lane b finalizes batch b (8 x float4 contiguous
// partial reads), shuffle-tree global sum.
__global__ __launch_bounds__(64) void finalize_kernel(
    const float* __restrict__ partials,
    const float* __restrict__ pos_sims,
    float*       __restrict__ out) {
  const int lane = threadIdx.x;   // 0..63 == batch index
  const float4* p = (const float4*)(partials + (size_t)lane * SLICES * 4);
  float sum = 0.0f;
  #pragma unroll
  for (int t = 0; t < SLICES; ++t) {
    const float4 v = p[t];
    sum += v.x + v.y + v.z + v.w;
  }
  const float ps = pos_sims[lane];
  float loss = logf(sum) + SHIFT - ps;
  #pragma unroll
  for (int off = 32; off > 0; off >>= 1) loss += __shfl_down(loss, off, 64);
  if (lane == 0) out[0] = loss / (2.0f * B);
}

extern "C" void kernel_launch(void* const* d_in, const int* in_sizes, int n_in,
                              void* d_out, int out_size, void* d_ws, size_t ws_size,
                              hipStream_t stream) {
  const float* childrens      = (const float*)d_in[0];   // (B,J,D)
  const float* childrens_pos  = (const float*)d_in[1];   // (B,J,D)
  const float* childrens_negs = (const float*)d_in[2];   // (B,K,M,D)
  const int*   gt_labels      = (const int*)d_in[3];     // (B,J)
  const int*   gt_label_negs  = (const int*)d_in[4];     // (B,K,M)
  float* out = (float*)d_out;

  float* partials = (float*)d_ws;          // NBLK*4 floats (per-wave slots)
  float* pos_sims = partials + NBLK * 4;   // B floats

  neg_partial_kernel<<<NBLK, 256, 0, stream>>>(
      childrens, childrens_pos, gt_labels, childrens_negs, gt_label_negs,
      partials, pos_sims);
  finalize_kernel<<<1, 64, 0, stream>>>(partials, pos_sims, out);
}